// Round 14
// baseline (61.507 us; speedup 1.0000x reference)
//
#include <hip/hip_runtime.h>
#include <hip/hip_bf16.h>

#define N_NODES 100000
#define N_EDGES 1250000
#define D_FEAT  64

#define BW        128                            // nodes per coarse bucket
#define NBK       ((N_NODES + BW - 1) / BW)      // 782 buckets
#define SCAP      16                             // staging entries/bucket; segment = 64B
#define NQ        (SCAP / 4)                     // 4 quads per segment
#define CHUNK     4096                           // edges per bin-block (proven)
#define PASS1_T   512
#define GRID_BIN  ((N_EDGES + CHUNK - 1) / CHUNK)                   // 306
#define GRID_CVT  ((N_NODES * D_FEAT / 8 + PASS1_T - 1) / PASS1_T)  // 1563
#define SPILL_CAP 65536
#define RCAP      1024                           // per-half records (mean 800, +8 sigma)
#define SRT_CAP   1024

// ---------------- pass 1 (fused): edge binning + x f32->bf16 ----------------
// bin blocks: LDS-stage edges per bucket, then dump counts + only the USED
// quads (16B granular) of each segment into this block's private window.
__global__ __launch_bounds__(PASS1_T)
void k_binvt(const float* __restrict__ x, unsigned short* __restrict__ xb,
             const int* __restrict__ src, const int* __restrict__ dst,
             unsigned char* __restrict__ cnt2, unsigned* __restrict__ buckets2,
             int* __restrict__ spill_cnt, int* __restrict__ spill) {
    __shared__ int      stg_cnt[NBK];        // 3.1 KB
    __shared__ unsigned stg[NBK][SCAP];      // 50 KB
    int tid = threadIdx.x;

    if (blockIdx.x >= GRID_BIN) {
        // ---- cvt part: one thread = 8 floats ----
        int i = (blockIdx.x - GRID_BIN) * PASS1_T + tid;
        const int total = N_NODES * D_FEAT / 8;            // 800000
        if (i >= total) return;
        const float4 f0 = *(const float4*)&x[i * 8];
        const float4 f1 = *(const float4*)&x[i * 8 + 4];
        const float fv[8] = {f0.x, f0.y, f0.z, f0.w, f1.x, f1.y, f1.z, f1.w};
        unsigned r[8];
        #pragma unroll
        for (int j = 0; j < 8; ++j) {
            unsigned u = __float_as_uint(fv[j]);
            r[j] = (u + 0x7FFFu + ((u >> 16) & 1u)) >> 16;   // round-nearest-even
        }
        uint4 o;
        o.x = r[0] | (r[1] << 16);
        o.y = r[2] | (r[3] << 16);
        o.z = r[4] | (r[5] << 16);
        o.w = r[6] | (r[7] << 16);
        *(uint4*)&xb[i * 8] = o;
        return;
    }

    // ---- bin part: record = (src << 7) | (dst & 127) ----
    for (int i = tid; i < NBK; i += PASS1_T) stg_cnt[i] = 0;
    __syncthreads();

    int base = blockIdx.x * CHUNK;
    #pragma unroll
    for (int r = 0; r < CHUNK / PASS1_T; ++r) {
        int e = base + r * PASS1_T + tid;
        if (e < N_EDGES) {
            int d = dst[e], s = src[e];
            int b = d >> 7;
            int pos = atomicAdd(&stg_cnt[b], 1);
            unsigned rec = ((unsigned)s << 7) | (unsigned)(d & (BW - 1));
            if (pos < SCAP) {
                stg[b][pos] = rec;
            } else {                               // staging overflow (rare)
                int sp = atomicAdd(spill_cnt, 1);
                if (sp < SPILL_CAP) { spill[2 * sp] = d; spill[2 * sp + 1] = s; }
            }
        }
    }
    __syncthreads();

    // dump counts
    unsigned char* myc = cnt2 + (size_t)blockIdx.x * NBK;
    for (int b = tid; b < NBK; b += PASS1_T) {
        int c = stg_cnt[b];
        myc[b] = (unsigned char)(c > SCAP ? SCAP : c);
    }
    // dump only used quads (write iff q*4 < count); addresses unchanged
    uint4* dstw = (uint4*)(buckets2 + (size_t)blockIdx.x * NBK * SCAP);
    const uint4* stg4 = (const uint4*)&stg[0][0];
    for (int i = tid; i < NBK * NQ; i += PASS1_T) {
        int b = i >> 2, q = i & 3;
        if (q * 4 < stg_cnt[b]) dstw[i] = stg4[i];
    }
}

// ---------------- pass 2: 2 blocks per bucket; segment load + sort + bf16 gather ----------------
__global__ __launch_bounds__(512)
void k_acc(const unsigned short* __restrict__ xb,
           const unsigned char* __restrict__ cnt2, const unsigned* __restrict__ buckets2,
           int* __restrict__ spill_cnt, int* __restrict__ spill,
           float* __restrict__ out) {
    __shared__ unsigned recs[RCAP];              // 4 KB: my half's records
    __shared__ unsigned srt[SRT_CAP];            // 4 KB
    __shared__ int rcnt;
    __shared__ int hist[64];
    __shared__ int offs[64 + 1];
    __shared__ int scan_tmp[64];
    int tid = threadIdx.x;
    int b    = blockIdx.x >> 1;                  // coarse bucket
    int half = blockIdx.x & 1;                   // which 64-node half

    if (tid == 0) rcnt = 0;
    if (tid < 64) hist[tid] = 0;
    __syncthreads();

    // load segments: thread t = bin-block t (306 < 512); read only used quads
    if (tid < GRID_BIN) {
        size_t segidx = (size_t)tid * NBK + b;
        int c = (int)cnt2[segidx];
        const uint4* seg4 = (const uint4*)(buckets2 + segidx * SCAP);
        uint4 q0 = make_uint4(0,0,0,0), q1 = q0, q2 = q0, q3 = q0;
        int nq = (c + 3) >> 2;
        if (nq > 0) q0 = seg4[0];
        if (nq > 1) q1 = seg4[1];
        if (nq > 2) q2 = seg4[2];
        if (nq > 3) q3 = seg4[3];
        unsigned t0[SCAP] = {q0.x,q0.y,q0.z,q0.w, q1.x,q1.y,q1.z,q1.w,
                             q2.x,q2.y,q2.z,q2.w, q3.x,q3.y,q3.z,q3.w};
        int m = 0;
        #pragma unroll
        for (int k = 0; k < SCAP; ++k)
            if (k < c && (int)((t0[k] >> 6) & 1u) == half) ++m;
        int rbase = 0;
        if (m > 0) rbase = atomicAdd(&rcnt, m);
        int w = 0;
        #pragma unroll
        for (int k = 0; k < SCAP; ++k) {
            if (k < c && (int)((t0[k] >> 6) & 1u) == half) {
                int idx = rbase + w;
                if (idx < RCAP) {
                    recs[idx] = t0[k];
                } else {                           // LDS overflow (never in practice)
                    int sp = atomicAdd(spill_cnt, 1);
                    if (sp < SPILL_CAP) {
                        spill[2 * sp]     = b * BW + (int)(t0[k] & (BW - 1));
                        spill[2 * sp + 1] = (int)(t0[k] >> 7);
                    }
                }
                ++w;
            }
        }
    }
    __syncthreads();
    int cnt = rcnt;
    if (cnt > RCAP) cnt = RCAP;

    // histogram by node-within-half
    for (int k = tid; k < cnt; k += 512) atomicAdd(&hist[recs[k] & 63], 1);
    __syncthreads();

    if (tid < 64) scan_tmp[tid] = hist[tid];
    __syncthreads();
    for (int d = 1; d < 64; d <<= 1) {
        int v = 0;
        if (tid < 64 && tid >= d) v = scan_tmp[tid - d];
        __syncthreads();
        if (tid < 64 && tid >= d) scan_tmp[tid] += v;
        __syncthreads();
    }
    if (tid < 64) {
        offs[tid + 1] = scan_tmp[tid] < SRT_CAP ? scan_tmp[tid] : SRT_CAP;
        if (tid == 0) offs[0] = 0;
        hist[tid] = 0;                           // reuse as scatter cursor
    }
    __syncthreads();

    // scatter into per-node sorted order (store src id)
    for (int k = tid; k < cnt; k += 512) {
        unsigned rec = recs[k];
        int d6 = rec & 63;
        int pos = atomicAdd(&hist[d6], 1);
        int idx = offs[d6] + pos;
        if (idx < SRT_CAP) srt[idx] = rec >> 7;
    }
    __syncthreads();

    // one 8-lane sub-group per node (64 sub-groups = 64 nodes)
    int sub = tid >> 3;                          // 0..63 = node within half
    int fl  = tid & 7;                           // uint4 slot within 128B bf16 row
    long long node = (long long)b * BW + (long long)half * 64 + sub;
    if (node >= N_NODES) return;
    int k0 = offs[sub], k1 = offs[sub + 1];
    #define BF16ACC(A, V)                                                   \
        A[0] += __uint_as_float((V).x << 16);                               \
        A[1] += __uint_as_float((V).x & 0xFFFF0000u);                       \
        A[2] += __uint_as_float((V).y << 16);                               \
        A[3] += __uint_as_float((V).y & 0xFFFF0000u);                       \
        A[4] += __uint_as_float((V).z << 16);                               \
        A[5] += __uint_as_float((V).z & 0xFFFF0000u);                       \
        A[6] += __uint_as_float((V).w << 16);                               \
        A[7] += __uint_as_float((V).w & 0xFFFF0000u);
    float a0[8] = {0,0,0,0,0,0,0,0};
    float a1[8] = {0,0,0,0,0,0,0,0};
    int k = k0;
    for (; k + 4 <= k1; k += 4) {                // 4 independent 16B loads in flight
        int s0 = srt[k], s1 = srt[k + 1], s2 = srt[k + 2], s3 = srt[k + 3];
        const uint4 v0 = *(const uint4*)&xb[(long long)s0 * D_FEAT + fl * 8];
        const uint4 v1 = *(const uint4*)&xb[(long long)s1 * D_FEAT + fl * 8];
        const uint4 v2 = *(const uint4*)&xb[(long long)s2 * D_FEAT + fl * 8];
        const uint4 v3 = *(const uint4*)&xb[(long long)s3 * D_FEAT + fl * 8];
        BF16ACC(a0, v0); BF16ACC(a1, v1); BF16ACC(a0, v2); BF16ACC(a1, v3);
    }
    for (; k < k1; ++k) {
        int s0 = srt[k];
        const uint4 v0 = *(const uint4*)&xb[(long long)s0 * D_FEAT + fl * 8];
        BF16ACC(a0, v0);
    }
    float4 f0, f1;
    f0.x = a0[0] + a1[0]; f0.y = a0[1] + a1[1];
    f0.z = a0[2] + a1[2]; f0.w = a0[3] + a1[3];
    f1.x = a0[4] + a1[4]; f1.y = a0[5] + a1[5];
    f1.z = a0[6] + a1[6]; f1.w = a0[7] + a1[7];
    *(float4*)&out[node * D_FEAT + fl * 8]     = f0;
    *(float4*)&out[node * D_FEAT + fl * 8 + 4] = f1;
    #undef BF16ACC
}

// ---------------- pass 3: spilled edges via atomics (f32 x, exact) ----------------
__global__ __launch_bounds__(256)
void k_spill(const float* __restrict__ x, const int* __restrict__ spill_cnt,
             const int* __restrict__ spill, float* __restrict__ out) {
    int sc = *spill_cnt;
    if (sc > SPILL_CAP) sc = SPILL_CAP;
    int total = sc * D_FEAT;
    int stride = gridDim.x * blockDim.x;
    for (int i = blockIdx.x * blockDim.x + threadIdx.x; i < total; i += stride) {
        int p = i >> 6, f = i & 63;
        int d = spill[2 * p], s = spill[2 * p + 1];
        atomicAdd(&out[(long long)d * D_FEAT + f], x[(long long)s * D_FEAT + f]);
    }
}

// ---------------- fallback: direct atomic scatter ----------------
__global__ __launch_bounds__(256)
void mp_scatter_atomic(const float* __restrict__ x,
                       const int* __restrict__ src,
                       const int* __restrict__ dst,
                       float* __restrict__ out) {
    long long t = (long long)blockIdx.x * blockDim.x + threadIdx.x;
    long long e = t >> 6;
    int f = (int)(t & 63);
    if (e >= N_EDGES) return;
    atomicAdd(&out[(long long)dst[e] * D_FEAT + f],
              x[(long long)src[e] * D_FEAT + f]);
}

extern "C" void kernel_launch(void* const* d_in, const int* in_sizes, int n_in,
                              void* d_out, int out_size, void* d_ws, size_t ws_size,
                              hipStream_t stream) {
    const float* x   = (const float*)d_in[0];
    const int*   ei  = (const int*)d_in[1];   // (2, N_EDGES): row 0 = src, row 1 = dst
    const int*   src = ei;
    const int*   dst = ei + N_EDGES;
    float* out = (float*)d_out;

    // ws layout:
    //   xb[6.4M ushort = 12.8MB]
    //   spill_cnt[1] spill[2*SPILL_CAP]  (ints)
    //   cnt2[GRID_BIN*NBK bytes, aligned]
    //   buckets2[GRID_BIN*NBK*SCAP uints = 15.3MB window]
    const size_t XB_INTS   = (size_t)N_NODES * D_FEAT / 2;           // 3,200,000
    const size_t SP_OFF    = XB_INTS;                                // ints
    const size_t CNT_OFF   = (SP_OFF + 1 + 2 * SPILL_CAP + 63) & ~(size_t)63;   // ints
    const size_t CNT_INTS  = ((size_t)GRID_BIN * NBK + 3) / 4;
    const size_t BKT_OFF   = (CNT_OFF + CNT_INTS + 63) & ~(size_t)63;
    const size_t WS_INTS   = BKT_OFF + (size_t)GRID_BIN * NBK * SCAP;
    const size_t WS_BYTES  = WS_INTS * sizeof(int);

    if (ws_size >= WS_BYTES) {
        int*            wsi       = (int*)d_ws;
        unsigned short* xb        = (unsigned short*)d_ws;
        int*            spill_cnt = wsi + SP_OFF;
        int*            spill     = wsi + SP_OFF + 1;
        unsigned char*  cnt2      = (unsigned char*)(wsi + CNT_OFF);
        unsigned*       buckets2  = (unsigned*)(wsi + BKT_OFF);

        (void)hipMemsetAsync(spill_cnt, 0, sizeof(int), stream);

        k_binvt<<<GRID_BIN + GRID_CVT, PASS1_T, 0, stream>>>(
            x, xb, src, dst, cnt2, buckets2, spill_cnt, spill);

        k_acc<<<NBK * 2, 512, 0, stream>>>(xb, cnt2, buckets2,
                                           spill_cnt, spill, out);

        k_spill<<<32, 256, 0, stream>>>(x, spill_cnt, spill, out);
    } else {
        (void)hipMemsetAsync(out, 0, (size_t)out_size * sizeof(float), stream);
        long long total = (long long)N_EDGES * D_FEAT;
        int block = 256;
        long long grid = (total + block - 1) / block;
        mp_scatter_atomic<<<(dim3)(unsigned)grid, block, 0, stream>>>(x, src, dst, out);
    }
}

// Round 15
// 59.069 us; speedup vs baseline: 1.0413x; 1.0413x over previous
//
#include <hip/hip_runtime.h>
#include <hip/hip_bf16.h>

#define N_NODES 100000
#define N_EDGES 1250000
#define D_FEAT  64

#define BW        128                            // nodes per coarse bucket
#define NBK       ((N_NODES + BW - 1) / BW)      // 782 buckets
#define SCAP      16                             // staging entries/bucket; segment = 64B
#define CHUNK     4096                           // edges per bin-block (proven)
#define PASS1_T   512
#define GRID_BIN  ((N_EDGES + CHUNK - 1) / CHUNK)                   // 306
#define GRID_CVT  ((N_NODES * D_FEAT / 8 + PASS1_T - 1) / PASS1_T)  // 1563
#define SPILL_CAP 65536
#define RCAP      2048                           // full-bucket records (mean 1600, +11 sigma)
#define SRT_CAP   2048

// ---------------- pass 1 (fused): edge binning + x f32->bf16 ----------------
// (EXACT round-13 measured version: full contiguous dump, no conditionals)
__global__ __launch_bounds__(PASS1_T)
void k_binvt(const float* __restrict__ x, unsigned short* __restrict__ xb,
             const int* __restrict__ src, const int* __restrict__ dst,
             unsigned char* __restrict__ cnt2, unsigned* __restrict__ buckets2,
             int* __restrict__ spill_cnt, int* __restrict__ spill) {
    __shared__ int      stg_cnt[NBK];        // 3.1 KB
    __shared__ unsigned stg[NBK][SCAP];      // 50 KB
    int tid = threadIdx.x;

    if (blockIdx.x >= GRID_BIN) {
        // ---- cvt part: one thread = 8 floats ----
        int i = (blockIdx.x - GRID_BIN) * PASS1_T + tid;
        const int total = N_NODES * D_FEAT / 8;            // 800000
        if (i >= total) return;
        const float4 f0 = *(const float4*)&x[i * 8];
        const float4 f1 = *(const float4*)&x[i * 8 + 4];
        const float fv[8] = {f0.x, f0.y, f0.z, f0.w, f1.x, f1.y, f1.z, f1.w};
        unsigned r[8];
        #pragma unroll
        for (int j = 0; j < 8; ++j) {
            unsigned u = __float_as_uint(fv[j]);
            r[j] = (u + 0x7FFFu + ((u >> 16) & 1u)) >> 16;   // round-nearest-even
        }
        uint4 o;
        o.x = r[0] | (r[1] << 16);
        o.y = r[2] | (r[3] << 16);
        o.z = r[4] | (r[5] << 16);
        o.w = r[6] | (r[7] << 16);
        *(uint4*)&xb[i * 8] = o;
        return;
    }

    // ---- bin part: record = (src << 7) | (dst & 127) ----
    for (int i = tid; i < NBK; i += PASS1_T) stg_cnt[i] = 0;
    __syncthreads();

    int base = blockIdx.x * CHUNK;
    #pragma unroll
    for (int r = 0; r < CHUNK / PASS1_T; ++r) {
        int e = base + r * PASS1_T + tid;
        if (e < N_EDGES) {
            int d = dst[e], s = src[e];
            int b = d >> 7;
            int pos = atomicAdd(&stg_cnt[b], 1);
            unsigned rec = ((unsigned)s << 7) | (unsigned)(d & (BW - 1));
            if (pos < SCAP) {
                stg[b][pos] = rec;
            } else {                               // staging overflow (rare)
                int sp = atomicAdd(spill_cnt, 1);
                if (sp < SPILL_CAP) { spill[2 * sp] = d; spill[2 * sp + 1] = s; }
            }
        }
    }
    __syncthreads();

    // dump: counts (clamped) + whole staging array, fully coalesced, no atomics
    unsigned char* myc = cnt2 + (size_t)blockIdx.x * NBK;
    for (int b = tid; b < NBK; b += PASS1_T) {
        int c = stg_cnt[b];
        myc[b] = (unsigned char)(c > SCAP ? SCAP : c);
    }
    unsigned* dstw = buckets2 + (size_t)blockIdx.x * NBK * SCAP;
    const unsigned* stg_flat = &stg[0][0];
    for (int i = tid; i < NBK * SCAP; i += PASS1_T) dstw[i] = stg_flat[i];
}

// ---------------- pass 2: ONE block per bucket (1024 thr); sort + bf16 gather ----------------
// Each block owns all 128 nodes of its bucket: segments read ONCE (no half
// filter), hist/scan/scatter once, then 128 sub-groups of 8 lanes gather.
__global__ __launch_bounds__(1024)
void k_acc(const unsigned short* __restrict__ xb,
           const unsigned char* __restrict__ cnt2, const unsigned* __restrict__ buckets2,
           int* __restrict__ spill_cnt, int* __restrict__ spill,
           float* __restrict__ out) {
    __shared__ unsigned recs[RCAP];              // 8 KB: this bucket's records
    __shared__ unsigned srt[SRT_CAP];            // 8 KB
    __shared__ int rcnt;
    __shared__ int hist[BW];
    __shared__ int offs[BW + 1];
    __shared__ int scan_tmp[BW];
    int tid = threadIdx.x;
    int b = blockIdx.x;                          // coarse bucket

    if (tid == 0) rcnt = 0;
    if (tid < BW) hist[tid] = 0;
    __syncthreads();

    // load segments: thread t = bin-block t (306 < 1024); full 64B segment
    if (tid < GRID_BIN) {
        size_t segidx = (size_t)tid * NBK + b;
        int c = (int)cnt2[segidx];
        const uint4* seg4 = (const uint4*)(buckets2 + segidx * SCAP);
        uint4 q0 = seg4[0], q1 = seg4[1], q2 = seg4[2], q3 = seg4[3];
        unsigned t0[SCAP] = {q0.x,q0.y,q0.z,q0.w, q1.x,q1.y,q1.z,q1.w,
                             q2.x,q2.y,q2.z,q2.w, q3.x,q3.y,q3.z,q3.w};
        int rbase = 0;
        if (c > 0) rbase = atomicAdd(&rcnt, c);
        #pragma unroll
        for (int k = 0; k < SCAP; ++k) {
            if (k < c) {
                int idx = rbase + k;
                if (idx < RCAP) {
                    recs[idx] = t0[k];
                } else {                           // LDS overflow (never in practice)
                    int sp = atomicAdd(spill_cnt, 1);
                    if (sp < SPILL_CAP) {
                        spill[2 * sp]     = b * BW + (int)(t0[k] & (BW - 1));
                        spill[2 * sp + 1] = (int)(t0[k] >> 7);
                    }
                }
            }
        }
    }
    __syncthreads();
    int cnt = rcnt;
    if (cnt > RCAP) cnt = RCAP;

    // histogram by node-within-bucket (7 bits)
    for (int k = tid; k < cnt; k += 1024) atomicAdd(&hist[recs[k] & (BW - 1)], 1);
    __syncthreads();

    if (tid < BW) scan_tmp[tid] = hist[tid];
    __syncthreads();
    for (int d = 1; d < BW; d <<= 1) {
        int v = 0;
        if (tid < BW && tid >= d) v = scan_tmp[tid - d];
        __syncthreads();
        if (tid < BW && tid >= d) scan_tmp[tid] += v;
        __syncthreads();
    }
    if (tid < BW) {
        offs[tid + 1] = scan_tmp[tid] < SRT_CAP ? scan_tmp[tid] : SRT_CAP;
        if (tid == 0) offs[0] = 0;
        hist[tid] = 0;                           // reuse as scatter cursor
    }
    __syncthreads();

    // scatter into per-node sorted order (store src id)
    for (int k = tid; k < cnt; k += 1024) {
        unsigned rec = recs[k];
        int d7 = rec & (BW - 1);
        int pos = atomicAdd(&hist[d7], 1);
        int idx = offs[d7] + pos;
        if (idx < SRT_CAP) srt[idx] = rec >> 7;
    }
    __syncthreads();

    // one 8-lane sub-group per node (128 sub-groups = 128 nodes)
    int sub = tid >> 3;                          // 0..127 = node within bucket
    int fl  = tid & 7;                           // uint4 slot within 128B bf16 row
    long long node = (long long)b * BW + sub;
    if (node >= N_NODES) return;
    int k0 = offs[sub], k1 = offs[sub + 1];
    #define BF16ACC(A, V)                                                   \
        A[0] += __uint_as_float((V).x << 16);                               \
        A[1] += __uint_as_float((V).x & 0xFFFF0000u);                       \
        A[2] += __uint_as_float((V).y << 16);                               \
        A[3] += __uint_as_float((V).y & 0xFFFF0000u);                       \
        A[4] += __uint_as_float((V).z << 16);                               \
        A[5] += __uint_as_float((V).z & 0xFFFF0000u);                       \
        A[6] += __uint_as_float((V).w << 16);                               \
        A[7] += __uint_as_float((V).w & 0xFFFF0000u);
    float a0[8] = {0,0,0,0,0,0,0,0};
    float a1[8] = {0,0,0,0,0,0,0,0};
    int k = k0;
    for (; k + 4 <= k1; k += 4) {                // 4 independent 16B loads in flight
        int s0 = srt[k], s1 = srt[k + 1], s2 = srt[k + 2], s3 = srt[k + 3];
        const uint4 v0 = *(const uint4*)&xb[(long long)s0 * D_FEAT + fl * 8];
        const uint4 v1 = *(const uint4*)&xb[(long long)s1 * D_FEAT + fl * 8];
        const uint4 v2 = *(const uint4*)&xb[(long long)s2 * D_FEAT + fl * 8];
        const uint4 v3 = *(const uint4*)&xb[(long long)s3 * D_FEAT + fl * 8];
        BF16ACC(a0, v0); BF16ACC(a1, v1); BF16ACC(a0, v2); BF16ACC(a1, v3);
    }
    for (; k < k1; ++k) {
        int s0 = srt[k];
        const uint4 v0 = *(const uint4*)&xb[(long long)s0 * D_FEAT + fl * 8];
        BF16ACC(a0, v0);
    }
    float4 f0, f1;
    f0.x = a0[0] + a1[0]; f0.y = a0[1] + a1[1];
    f0.z = a0[2] + a1[2]; f0.w = a0[3] + a1[3];
    f1.x = a0[4] + a1[4]; f1.y = a0[5] + a1[5];
    f1.z = a0[6] + a1[6]; f1.w = a0[7] + a1[7];
    *(float4*)&out[node * D_FEAT + fl * 8]     = f0;
    *(float4*)&out[node * D_FEAT + fl * 8 + 4] = f1;
    #undef BF16ACC
}

// ---------------- pass 3: spilled edges via atomics (f32 x, exact) ----------------
__global__ __launch_bounds__(256)
void k_spill(const float* __restrict__ x, const int* __restrict__ spill_cnt,
             const int* __restrict__ spill, float* __restrict__ out) {
    int sc = *spill_cnt;
    if (sc > SPILL_CAP) sc = SPILL_CAP;
    int total = sc * D_FEAT;
    int stride = gridDim.x * blockDim.x;
    for (int i = blockIdx.x * blockDim.x + threadIdx.x; i < total; i += stride) {
        int p = i >> 6, f = i & 63;
        int d = spill[2 * p], s = spill[2 * p + 1];
        atomicAdd(&out[(long long)d * D_FEAT + f], x[(long long)s * D_FEAT + f]);
    }
}

// ---------------- fallback: direct atomic scatter ----------------
__global__ __launch_bounds__(256)
void mp_scatter_atomic(const float* __restrict__ x,
                       const int* __restrict__ src,
                       const int* __restrict__ dst,
                       float* __restrict__ out) {
    long long t = (long long)blockIdx.x * blockDim.x + threadIdx.x;
    long long e = t >> 6;
    int f = (int)(t & 63);
    if (e >= N_EDGES) return;
    atomicAdd(&out[(long long)dst[e] * D_FEAT + f],
              x[(long long)src[e] * D_FEAT + f]);
}

extern "C" void kernel_launch(void* const* d_in, const int* in_sizes, int n_in,
                              void* d_out, int out_size, void* d_ws, size_t ws_size,
                              hipStream_t stream) {
    const float* x   = (const float*)d_in[0];
    const int*   ei  = (const int*)d_in[1];   // (2, N_EDGES): row 0 = src, row 1 = dst
    const int*   src = ei;
    const int*   dst = ei + N_EDGES;
    float* out = (float*)d_out;

    // ws layout:
    //   xb[6.4M ushort = 12.8MB]
    //   spill_cnt[1] spill[2*SPILL_CAP]  (ints)
    //   cnt2[GRID_BIN*NBK bytes, aligned]
    //   buckets2[GRID_BIN*NBK*SCAP uints = 15.3MB]
    const size_t XB_INTS   = (size_t)N_NODES * D_FEAT / 2;           // 3,200,000
    const size_t SP_OFF    = XB_INTS;                                // ints
    const size_t CNT_OFF   = (SP_OFF + 1 + 2 * SPILL_CAP + 63) & ~(size_t)63;   // ints
    const size_t CNT_INTS  = ((size_t)GRID_BIN * NBK + 3) / 4;
    const size_t BKT_OFF   = (CNT_OFF + CNT_INTS + 63) & ~(size_t)63;
    const size_t WS_INTS   = BKT_OFF + (size_t)GRID_BIN * NBK * SCAP;
    const size_t WS_BYTES  = WS_INTS * sizeof(int);

    if (ws_size >= WS_BYTES) {
        int*            wsi       = (int*)d_ws;
        unsigned short* xb        = (unsigned short*)d_ws;
        int*            spill_cnt = wsi + SP_OFF;
        int*            spill     = wsi + SP_OFF + 1;
        unsigned char*  cnt2      = (unsigned char*)(wsi + CNT_OFF);
        unsigned*       buckets2  = (unsigned*)(wsi + BKT_OFF);

        (void)hipMemsetAsync(spill_cnt, 0, sizeof(int), stream);

        k_binvt<<<GRID_BIN + GRID_CVT, PASS1_T, 0, stream>>>(
            x, xb, src, dst, cnt2, buckets2, spill_cnt, spill);

        k_acc<<<NBK, 1024, 0, stream>>>(xb, cnt2, buckets2,
                                        spill_cnt, spill, out);

        k_spill<<<32, 256, 0, stream>>>(x, spill_cnt, spill, out);
    } else {
        (void)hipMemsetAsync(out, 0, (size_t)out_size * sizeof(float), stream);
        long long total = (long long)N_EDGES * D_FEAT;
        int block = 256;
        long long grid = (total + block - 1) / block;
        mp_scatter_atomic<<<(dim3)(unsigned)grid, block, 0, stream>>>(x, src, dst, out);
    }
}

// Round 16
// 54.779 us; speedup vs baseline: 1.1228x; 1.0783x over previous
//
#include <hip/hip_runtime.h>
#include <hip/hip_bf16.h>

#define N_NODES 100000
#define N_EDGES 1250000
#define D_FEAT  64

#define BW        128                            // nodes per coarse bucket
#define NBK       ((N_NODES + BW - 1) / BW)      // 782 buckets
#define SCAP      16                             // staging entries/bucket; segment = 64B
#define CHUNK     4096                           // edges per bin-block (proven)
#define PASS1_T   512
#define GRID_BIN  ((N_EDGES + CHUNK - 1) / CHUNK)                   // 306
#define GRID_CVT  ((N_NODES * D_FEAT / 8 + PASS1_T - 1) / PASS1_T)  // 1563
#define SPILL_CAP 65536
#define SRT_CAP   1024                           // per 64-node half (mean 800, +8 sigma)
#define OVF_CAP   64

// ---------------- pass 1 (fused): edge binning + x f32->bf16 ----------------
// (EXACT round-13 measured version: full contiguous dump, no conditionals)
__global__ __launch_bounds__(PASS1_T)
void k_binvt(const float* __restrict__ x, unsigned short* __restrict__ xb,
             const int* __restrict__ src, const int* __restrict__ dst,
             unsigned char* __restrict__ cnt2, unsigned* __restrict__ buckets2,
             int* __restrict__ spill_cnt, int* __restrict__ spill) {
    __shared__ int      stg_cnt[NBK];        // 3.1 KB
    __shared__ unsigned stg[NBK][SCAP];      // 50 KB
    int tid = threadIdx.x;

    if (blockIdx.x >= GRID_BIN) {
        // ---- cvt part: one thread = 8 floats ----
        int i = (blockIdx.x - GRID_BIN) * PASS1_T + tid;
        const int total = N_NODES * D_FEAT / 8;            // 800000
        if (i >= total) return;
        const float4 f0 = *(const float4*)&x[i * 8];
        const float4 f1 = *(const float4*)&x[i * 8 + 4];
        const float fv[8] = {f0.x, f0.y, f0.z, f0.w, f1.x, f1.y, f1.z, f1.w};
        unsigned r[8];
        #pragma unroll
        for (int j = 0; j < 8; ++j) {
            unsigned u = __float_as_uint(fv[j]);
            r[j] = (u + 0x7FFFu + ((u >> 16) & 1u)) >> 16;   // round-nearest-even
        }
        uint4 o;
        o.x = r[0] | (r[1] << 16);
        o.y = r[2] | (r[3] << 16);
        o.z = r[4] | (r[5] << 16);
        o.w = r[6] | (r[7] << 16);
        *(uint4*)&xb[i * 8] = o;
        return;
    }

    // ---- bin part: record = (src << 7) | (dst & 127) ----
    for (int i = tid; i < NBK; i += PASS1_T) stg_cnt[i] = 0;
    __syncthreads();

    int base = blockIdx.x * CHUNK;
    #pragma unroll
    for (int r = 0; r < CHUNK / PASS1_T; ++r) {
        int e = base + r * PASS1_T + tid;
        if (e < N_EDGES) {
            int d = dst[e], s = src[e];
            int b = d >> 7;
            int pos = atomicAdd(&stg_cnt[b], 1);
            unsigned rec = ((unsigned)s << 7) | (unsigned)(d & (BW - 1));
            if (pos < SCAP) {
                stg[b][pos] = rec;
            } else {                               // staging overflow (rare)
                int sp = atomicAdd(spill_cnt, 1);
                if (sp < SPILL_CAP) { spill[2 * sp] = d; spill[2 * sp + 1] = s; }
            }
        }
    }
    __syncthreads();

    // dump: counts (clamped) + whole staging array, fully coalesced, no atomics
    unsigned char* myc = cnt2 + (size_t)blockIdx.x * NBK;
    for (int b = tid; b < NBK; b += PASS1_T) {
        int c = stg_cnt[b];
        myc[b] = (unsigned char)(c > SCAP ? SCAP : c);
    }
    unsigned* dstw = buckets2 + (size_t)blockIdx.x * NBK * SCAP;
    const unsigned* stg_flat = &stg[0][0];
    for (int i = tid; i < NBK * SCAP; i += PASS1_T) dstw[i] = stg_flat[i];
}

// ---------------- pass 2: 2 blocks/bucket; register-direct sort + bf16 gather ----------------
// r13 structure, minus the recs[] LDS round-trip (records stay in the loading
// thread's registers across hist/scan) and with spill handling folded in.
__global__ __launch_bounds__(512)
void k_acc(const unsigned short* __restrict__ xb,
           const unsigned char* __restrict__ cnt2, const unsigned* __restrict__ buckets2,
           const int* __restrict__ spill_cnt, const int* __restrict__ spill,
           float* __restrict__ out) {
    __shared__ unsigned srt[SRT_CAP];            // 4 KB
    __shared__ unsigned ovf[OVF_CAP];            // srt-overflow records (never in practice)
    __shared__ int ovf_cnt;
    __shared__ int hist[64];
    __shared__ int offs[64 + 1];
    __shared__ int scan_tmp[64];
    int tid = threadIdx.x;
    int b    = blockIdx.x >> 1;                  // coarse bucket
    int half = blockIdx.x & 1;                   // which 64-node half

    if (tid == 0) ovf_cnt = 0;
    if (tid < 64) hist[tid] = 0;
    __syncthreads();

    // load segment into REGISTERS (thread t = bin-block t) + filtered histogram
    unsigned t0[SCAP];
    int c = 0;
    if (tid < GRID_BIN) {
        size_t segidx = (size_t)tid * NBK + b;
        c = (int)cnt2[segidx];
        const uint4* seg4 = (const uint4*)(buckets2 + segidx * SCAP);
        uint4 q0 = seg4[0], q1 = seg4[1], q2 = seg4[2], q3 = seg4[3];
        t0[0]=q0.x; t0[1]=q0.y; t0[2]=q0.z; t0[3]=q0.w;
        t0[4]=q1.x; t0[5]=q1.y; t0[6]=q1.z; t0[7]=q1.w;
        t0[8]=q2.x; t0[9]=q2.y; t0[10]=q2.z; t0[11]=q2.w;
        t0[12]=q3.x; t0[13]=q3.y; t0[14]=q3.z; t0[15]=q3.w;
        #pragma unroll
        for (int k = 0; k < SCAP; ++k)
            if (k < c && (int)((t0[k] >> 6) & 1u) == half)
                atomicAdd(&hist[t0[k] & 63], 1);
    }
    __syncthreads();

    if (tid < 64) scan_tmp[tid] = hist[tid];
    __syncthreads();
    for (int d = 1; d < 64; d <<= 1) {
        int v = 0;
        if (tid < 64 && tid >= d) v = scan_tmp[tid - d];
        __syncthreads();
        if (tid < 64 && tid >= d) scan_tmp[tid] += v;
        __syncthreads();
    }
    if (tid < 64) {
        offs[tid + 1] = scan_tmp[tid] < SRT_CAP ? scan_tmp[tid] : SRT_CAP;
        if (tid == 0) offs[0] = 0;
        hist[tid] = 0;                           // reuse as scatter cursor
    }
    __syncthreads();

    // scatter straight from registers into per-node sorted order (store src id)
    if (tid < GRID_BIN) {
        #pragma unroll
        for (int k = 0; k < SCAP; ++k) {
            if (k < c && (int)((t0[k] >> 6) & 1u) == half) {
                int d6 = t0[k] & 63;
                int pos = atomicAdd(&hist[d6], 1);
                int idx = offs[d6] + pos;
                if (idx < offs[d6 + 1]) {
                    srt[idx] = t0[k] >> 7;
                } else {                           // clamped tail -> local overflow
                    int o = atomicAdd(&ovf_cnt, 1);
                    if (o < OVF_CAP) ovf[o] = t0[k];
                }
            }
        }
    }
    __syncthreads();

    // one 8-lane sub-group per node (64 sub-groups = 64 nodes)
    int sub = tid >> 3;                          // 0..63 = node within half
    int fl  = tid & 7;                           // uint4 slot within 128B bf16 row
    long long node = (long long)b * BW + (long long)half * 64 + sub;
    if (node >= N_NODES) return;
    int k0 = offs[sub], k1 = offs[sub + 1];
    #define BF16ACC(A, V)                                                   \
        A[0] += __uint_as_float((V).x << 16);                               \
        A[1] += __uint_as_float((V).x & 0xFFFF0000u);                       \
        A[2] += __uint_as_float((V).y << 16);                               \
        A[3] += __uint_as_float((V).y & 0xFFFF0000u);                       \
        A[4] += __uint_as_float((V).z << 16);                               \
        A[5] += __uint_as_float((V).z & 0xFFFF0000u);                       \
        A[6] += __uint_as_float((V).w << 16);                               \
        A[7] += __uint_as_float((V).w & 0xFFFF0000u);
    float a0[8] = {0,0,0,0,0,0,0,0};
    float a1[8] = {0,0,0,0,0,0,0,0};
    int k = k0;
    for (; k + 4 <= k1; k += 4) {                // 4 independent 16B loads in flight
        int s0 = srt[k], s1 = srt[k + 1], s2 = srt[k + 2], s3 = srt[k + 3];
        const uint4 v0 = *(const uint4*)&xb[(long long)s0 * D_FEAT + fl * 8];
        const uint4 v1 = *(const uint4*)&xb[(long long)s1 * D_FEAT + fl * 8];
        const uint4 v2 = *(const uint4*)&xb[(long long)s2 * D_FEAT + fl * 8];
        const uint4 v3 = *(const uint4*)&xb[(long long)s3 * D_FEAT + fl * 8];
        BF16ACC(a0, v0); BF16ACC(a1, v1); BF16ACC(a0, v2); BF16ACC(a1, v3);
    }
    for (; k < k1; ++k) {
        int s0 = srt[k];
        const uint4 v0 = *(const uint4*)&xb[(long long)s0 * D_FEAT + fl * 8];
        BF16ACC(a0, v0);
    }

    // folded spill handling: binvt staging spills (global list, tiny)
    int sc = *spill_cnt;
    if (sc > SPILL_CAP) sc = SPILL_CAP;
    for (int i = 0; i < sc; ++i) {
        if ((long long)spill[2 * i] == node) {
            int s = spill[2 * i + 1];
            const uint4 v0 = *(const uint4*)&xb[(long long)s * D_FEAT + fl * 8];
            BF16ACC(a0, v0);
        }
    }
    // local srt-overflow records
    int oc = ovf_cnt;
    if (oc > OVF_CAP) oc = OVF_CAP;
    for (int i = 0; i < oc; ++i) {
        unsigned rec = ovf[i];
        if ((int)(rec & 63) == sub) {
            int s = (int)(rec >> 7);
            const uint4 v0 = *(const uint4*)&xb[(long long)s * D_FEAT + fl * 8];
            BF16ACC(a0, v0);
        }
    }

    float4 f0, f1;
    f0.x = a0[0] + a1[0]; f0.y = a0[1] + a1[1];
    f0.z = a0[2] + a1[2]; f0.w = a0[3] + a1[3];
    f1.x = a0[4] + a1[4]; f1.y = a0[5] + a1[5];
    f1.z = a0[6] + a1[6]; f1.w = a0[7] + a1[7];
    *(float4*)&out[node * D_FEAT + fl * 8]     = f0;
    *(float4*)&out[node * D_FEAT + fl * 8 + 4] = f1;
    #undef BF16ACC
}

// ---------------- fallback: direct atomic scatter ----------------
__global__ __launch_bounds__(256)
void mp_scatter_atomic(const float* __restrict__ x,
                       const int* __restrict__ src,
                       const int* __restrict__ dst,
                       float* __restrict__ out) {
    long long t = (long long)blockIdx.x * blockDim.x + threadIdx.x;
    long long e = t >> 6;
    int f = (int)(t & 63);
    if (e >= N_EDGES) return;
    atomicAdd(&out[(long long)dst[e] * D_FEAT + f],
              x[(long long)src[e] * D_FEAT + f]);
}

extern "C" void kernel_launch(void* const* d_in, const int* in_sizes, int n_in,
                              void* d_out, int out_size, void* d_ws, size_t ws_size,
                              hipStream_t stream) {
    const float* x   = (const float*)d_in[0];
    const int*   ei  = (const int*)d_in[1];   // (2, N_EDGES): row 0 = src, row 1 = dst
    const int*   src = ei;
    const int*   dst = ei + N_EDGES;
    float* out = (float*)d_out;

    // ws layout:
    //   xb[6.4M ushort = 12.8MB]
    //   spill_cnt[1] spill[2*SPILL_CAP]  (ints)
    //   cnt2[GRID_BIN*NBK bytes, aligned]
    //   buckets2[GRID_BIN*NBK*SCAP uints = 15.3MB]
    const size_t XB_INTS   = (size_t)N_NODES * D_FEAT / 2;           // 3,200,000
    const size_t SP_OFF    = XB_INTS;                                // ints
    const size_t CNT_OFF   = (SP_OFF + 1 + 2 * SPILL_CAP + 63) & ~(size_t)63;   // ints
    const size_t CNT_INTS  = ((size_t)GRID_BIN * NBK + 3) / 4;
    const size_t BKT_OFF   = (CNT_OFF + CNT_INTS + 63) & ~(size_t)63;
    const size_t WS_INTS   = BKT_OFF + (size_t)GRID_BIN * NBK * SCAP;
    const size_t WS_BYTES  = WS_INTS * sizeof(int);

    if (ws_size >= WS_BYTES) {
        int*            wsi       = (int*)d_ws;
        unsigned short* xb        = (unsigned short*)d_ws;
        int*            spill_cnt = wsi + SP_OFF;
        int*            spill     = wsi + SP_OFF + 1;
        unsigned char*  cnt2      = (unsigned char*)(wsi + CNT_OFF);
        unsigned*       buckets2  = (unsigned*)(wsi + BKT_OFF);

        (void)hipMemsetAsync(spill_cnt, 0, sizeof(int), stream);

        k_binvt<<<GRID_BIN + GRID_CVT, PASS1_T, 0, stream>>>(
            x, xb, src, dst, cnt2, buckets2, spill_cnt, spill);

        k_acc<<<NBK * 2, 512, 0, stream>>>(xb, cnt2, buckets2,
                                           spill_cnt, spill, out);
    } else {
        (void)hipMemsetAsync(out, 0, (size_t)out_size * sizeof(float), stream);
        long long total = (long long)N_EDGES * D_FEAT;
        int block = 256;
        long long grid = (total + block - 1) / block;
        mp_scatter_atomic<<<(dim3)(unsigned)grid, block, 0, stream>>>(x, src, dst, out);
    }
}